// Round 4
// baseline (1369.783 us; speedup 1.0000x reference)
//
#include <hip/hip_runtime.h>
#include <hip/hip_bf16.h>

#define D 128
#define NPW 8  // nodes per wave in node_tables

// wrT[m*64 + r] = dot(W[m, :], rel[r, :])   (m in [0,256), transposed layout)
__global__ __launch_bounds__(256) void compute_wr(const float* __restrict__ W,
                                                  const float* __restrict__ rel,
                                                  float* __restrict__ wrT) {
    int r = blockIdx.x;
    int m = threadIdx.x;
    const float4* wrow = (const float4*)(W + (size_t)m * D);
    const float4* rrow = (const float4*)(rel + (size_t)r * D);
    float s = 0.f;
#pragma unroll
    for (int k = 0; k < D / 4; ++k) {
        float4 a = wrow[k];
        float4 b = rrow[k];
        s += a.x * b.x + a.y * b.y + a.z * b.z + a.w * b.w;
    }
    wrT[(size_t)m * 64 + r] = s;
}

// Degree count
__global__ __launch_bounds__(256) void count_deg(const int* __restrict__ head,
                                                 const int* __restrict__ tail,
                                                 int* __restrict__ deg_u,
                                                 int* __restrict__ deg_i, int E) {
    int e = blockIdx.x * 256 + threadIdx.x;
    if (e >= E) return;
    atomicAdd(deg_u + head[e], 1);
    atomicAdd(deg_i + tail[e], 1);
}

// ---- two-level exclusive scan (N <= nb*4096, nb <= 64) ----
__global__ __launch_bounds__(1024) void scan_bsum(const int* __restrict__ deg,
                                                  int* __restrict__ bsum, int N) {
    __shared__ int lds[1024];
    int b = blockIdx.x, tid = threadIdx.x;
    int base = b * 4096 + tid * 4;
    int s = 0;
#pragma unroll
    for (int j = 0; j < 4; ++j) { int i = base + j; if (i < N) s += deg[i]; }
    lds[tid] = s;
    __syncthreads();
    for (int off = 1; off < 1024; off <<= 1) {
        int t = (tid >= off) ? lds[tid - off] : 0;
        __syncthreads();
        lds[tid] += t;
        __syncthreads();
    }
    if (tid == 1023) bsum[b] = lds[1023];
}

__global__ __launch_bounds__(64) void scan_off(const int* __restrict__ bsum,
                                               int* __restrict__ boff, int nb) {
    int tid = threadIdx.x;
    int v = (tid < nb) ? bsum[tid] : 0;
    int incl = v;
    for (int off = 1; off < 64; off <<= 1) {
        int t = __shfl_up(incl, off, 64);
        if (tid >= off) incl += t;
    }
    if (tid < nb) boff[tid] = incl - v;
    if (tid == 63) boff[nb] = incl;  // grand total
}

__global__ __launch_bounds__(1024) void scan_write(const int* __restrict__ deg,
                                                   const int* __restrict__ boff,
                                                   int* __restrict__ rowptr,
                                                   int* __restrict__ cur, int N, int nb) {
    __shared__ int lds[1024];
    int b = blockIdx.x, tid = threadIdx.x;
    int base = b * 4096 + tid * 4;
    int v[4];
    int s = 0;
#pragma unroll
    for (int j = 0; j < 4; ++j) { int i = base + j; v[j] = (i < N) ? deg[i] : 0; s += v[j]; }
    lds[tid] = s;
    __syncthreads();
    for (int off = 1; off < 1024; off <<= 1) {
        int t = (tid >= off) ? lds[tid - off] : 0;
        __syncthreads();
        lds[tid] += t;
        __syncthreads();
    }
    int run = boff[b] + lds[tid] - s;
#pragma unroll
    for (int j = 0; j < 4; ++j) {
        int i = base + j;
        if (i < N) { rowptr[i] = run; cur[i] = run; run += v[j]; }
    }
    if (b == 0 && tid == 0) rowptr[N] = boff[nb];
}

// Scatter edge ids into CSR edge lists using cursor fetch-add.
__global__ __launch_bounds__(256) void fill_elist(const int* __restrict__ head,
                                                  const int* __restrict__ tail,
                                                  int* __restrict__ cur_u,
                                                  int* __restrict__ cur_i,
                                                  int* __restrict__ elist_u,
                                                  int* __restrict__ elist_i, int E) {
    int e = blockIdx.x * 256 + threadIdx.x;
    if (e >= E) return;
    int su = atomicAdd(cur_u + head[e], 1);
    elist_u[su] = e;
    int si = atomicAdd(cur_i + tail[e], 1);
    elist_i[si] = e;
}

// out[n*64 + r] = dot(rows[n, :], wrT[:, r])  -- wrT is [128][64] slice.
// Wave handles NPW nodes; lane = r. Row elements broadcast via shfl.
__global__ __launch_bounds__(256) void node_tables(const float* __restrict__ rows,
                                                   const float* __restrict__ wrT,
                                                   float* __restrict__ out, int N) {
    int wid = (int)((blockIdx.x * 256 + threadIdx.x) >> 6);
    int lane = threadIdx.x & 63;
    int n0 = wid * NPW;
    if (n0 >= N) return;
    float2 row[NPW];
#pragma unroll
    for (int i = 0; i < NPW; ++i) {
        int n = n0 + i;
        row[i] = (n < N) ? ((const float2*)(rows + (size_t)n * D))[lane]
                         : make_float2(0.f, 0.f);
    }
    float acc[NPW];
#pragma unroll
    for (int i = 0; i < NPW; ++i) acc[i] = 0.f;
    for (int kk = 0; kk < 64; ++kk) {
        float w0 = wrT[(size_t)(2 * kk) * 64 + lane];
        float w1 = wrT[(size_t)(2 * kk + 1) * 64 + lane];
#pragma unroll
        for (int i = 0; i < NPW; ++i) {
            float x = __shfl(row[i].x, kk, 64);
            float y = __shfl(row[i].y, kk, 64);
            acc[i] += x * w0 + y * w1;
        }
    }
#pragma unroll
    for (int i = 0; i < NPW; ++i) {
        int n = n0 + i;
        if (n < N) out[(size_t)n * 64 + lane] = acc[i];
    }
}

// e_exp[e] = exp(leakyrelu(alpha[head,r] + beta[tail,r]))
__global__ __launch_bounds__(256) void edge_weights(const int* __restrict__ head,
                                                    const int* __restrict__ tail,
                                                    const int* __restrict__ etype,
                                                    const float* __restrict__ alpha,
                                                    const float* __restrict__ beta,
                                                    float* __restrict__ e_exp, int E) {
    int e = blockIdx.x * 256 + threadIdx.x;
    if (e >= E) return;
    int h = head[e], t = tail[e], r = etype[e];
    float s = alpha[(size_t)h * 64 + r] + beta[(size_t)t * 64 + r];
    s = s > 0.f ? s : 0.2f * s;  // LeakyReLU(0.2)
    e_exp[e] = expf(s);
}

// One wavefront per destination node:
//   acc = sum_j e_j * src_rows[other[j]];  esum = sum_j e_j
//   agg = acc/esum + self;  out = self + agg/max(||agg||,1e-8)
__global__ __launch_bounds__(256) void agg_nodes(const float* __restrict__ src_rows,
                                                 const float* __restrict__ self_rows,
                                                 const float* __restrict__ e_exp,
                                                 const int* __restrict__ rowptr,
                                                 const int* __restrict__ elist,
                                                 const int* __restrict__ other_idx,
                                                 float* __restrict__ dst, int N) {
    int node = (int)((blockIdx.x * (size_t)blockDim.x + threadIdx.x) >> 6);
    int lane = threadIdx.x & 63;
    if (node >= N) return;
    int beg = rowptr[node];
    int end = rowptr[node + 1];
    float ax = 0.f, ay = 0.f, esum = 0.f;
    for (int p = beg; p < end; ++p) {
        int e = elist[p];
        float w = e_exp[e];
        int src = other_idx[e];
        float2 v = ((const float2*)(src_rows + (size_t)src * D))[lane];
        ax += w * v.x;
        ay += w * v.y;
        esum += w;
    }
    float inv_e = (end > beg) ? 1.f / esum : 0.f;
    float2 self = ((const float2*)(self_rows + (size_t)node * D))[lane];
    float gx = ax * inv_e + self.x;
    float gy = ay * inv_e + self.y;
    float n2 = gx * gx + gy * gy;
#pragma unroll
    for (int off = 32; off; off >>= 1) n2 += __shfl_xor(n2, off, 64);
    float inv = 1.f / fmaxf(sqrtf(n2), 1e-8f);
    float2 o;
    o.x = self.x + gx * inv;
    o.y = self.y + gy * inv;
    ((float2*)(dst + (size_t)node * D))[lane] = o;
}

extern "C" void kernel_launch(void* const* d_in, const int* in_sizes, int n_in,
                              void* d_out, int out_size, void* d_ws, size_t ws_size,
                              hipStream_t stream) {
    const float* user = (const float*)d_in[0];
    const float* rel  = (const float*)d_in[1];
    const float* ent  = (const float*)d_in[2];
    const float* W    = (const float*)d_in[3];
    const int* eidx   = (const int*)d_in[4];
    const int* etype  = (const int*)d_in[5];

    int Nu = in_sizes[0] / D;
    int R  = in_sizes[1] / D;
    int Ne = in_sizes[2] / D;
    int E  = in_sizes[5];
    const int* head = eidx;
    const int* tail = eidx + E;

    float* out_usr = (float*)d_out;
    float* out_ent = out_usr + (size_t)Nu * D;

    // alpha/beta tables live in d_out (dead scratch until hop-1 aggs write it;
    // edge_weights finishes reading them before aggs run, stream-ordered).
    float* alpha = (float*)d_out;
    float* beta  = alpha + (size_t)Nu * 64;

    // Workspace layout
    float* fp = (float*)d_ws;
    float* usr_ws = fp; fp += (size_t)Nu * D;
    float* ent_ws = fp; fp += (size_t)Ne * D;
    float* e_exp  = fp; fp += E;
    float* wrT    = fp; fp += (size_t)R * 2 * D;  // [256][64] transposed
    int* ip = (int*)fp;
    int* deg_u    = ip; ip += Nu;      // contiguous with deg_i for one memset
    int* deg_i    = ip; ip += Ne;
    int* cur_u    = ip; ip += Nu;
    int* cur_i    = ip; ip += Ne;
    int* rowptr_u = ip; ip += Nu + 1;
    int* rowptr_i = ip; ip += Ne + 1;
    int* elist_u  = ip; ip += E;
    int* elist_i  = ip; ip += E;
    int* bsum_u   = ip; ip += 64;
    int* bsum_i   = ip; ip += 64;
    int* boff_u   = ip; ip += 65;
    int* boff_i   = ip; ip += 65;

    int nb_u = (Nu + 4095) / 4096;
    int nb_i = (Ne + 4095) / 4096;

    // ---- Build CSR (once; graph is static across hops) ----
    hipMemsetAsync(deg_u, 0, (size_t)(Nu + Ne) * sizeof(int), stream);
    compute_wr<<<R, 256, 0, stream>>>(W, rel, wrT);
    count_deg<<<(E + 255) / 256, 256, 0, stream>>>(head, tail, deg_u, deg_i, E);
    scan_bsum<<<nb_u, 1024, 0, stream>>>(deg_u, bsum_u, Nu);
    scan_off<<<1, 64, 0, stream>>>(bsum_u, boff_u, nb_u);
    scan_write<<<nb_u, 1024, 0, stream>>>(deg_u, boff_u, rowptr_u, cur_u, Nu, nb_u);
    scan_bsum<<<nb_i, 1024, 0, stream>>>(deg_i, bsum_i, Ne);
    scan_off<<<1, 64, 0, stream>>>(bsum_i, boff_i, nb_i);
    scan_write<<<nb_i, 1024, 0, stream>>>(deg_i, boff_i, rowptr_i, cur_i, Ne, nb_i);
    fill_elist<<<(E + 255) / 256, 256, 0, stream>>>(head, tail, cur_u, cur_i,
                                                    elist_u, elist_i, E);

    int tbl_u = (Nu + NPW * 4 - 1) / (NPW * 4);
    int tbl_i = (Ne + NPW * 4 - 1) / (NPW * 4);
    int eb = (E + 255) / 256;

    // ---- Hop 0: inputs -> ws ----
    node_tables<<<tbl_u, 256, 0, stream>>>(user, wrT, alpha, Nu);
    node_tables<<<tbl_i, 256, 0, stream>>>(ent, wrT + (size_t)D * 64, beta, Ne);
    edge_weights<<<eb, 256, 0, stream>>>(head, tail, etype, alpha, beta, e_exp, E);
    agg_nodes<<<(Nu + 3) / 4, 256, 0, stream>>>(ent, user, e_exp, rowptr_u, elist_u,
                                                tail, usr_ws, Nu);
    agg_nodes<<<(Ne + 3) / 4, 256, 0, stream>>>(user, ent, e_exp, rowptr_i, elist_i,
                                                head, ent_ws, Ne);

    // ---- Hop 1: ws -> d_out ----
    node_tables<<<tbl_u, 256, 0, stream>>>(usr_ws, wrT, alpha, Nu);
    node_tables<<<tbl_i, 256, 0, stream>>>(ent_ws, wrT + (size_t)D * 64, beta, Ne);
    edge_weights<<<eb, 256, 0, stream>>>(head, tail, etype, alpha, beta, e_exp, E);
    agg_nodes<<<(Nu + 3) / 4, 256, 0, stream>>>(ent_ws, usr_ws, e_exp, rowptr_u, elist_u,
                                                tail, out_usr, Nu);
    agg_nodes<<<(Ne + 3) / 4, 256, 0, stream>>>(usr_ws, ent_ws, e_exp, rowptr_i, elist_i,
                                                head, out_ent, Ne);
}

// Round 5
// 984.522 us; speedup vs baseline: 1.3913x; 1.3913x over previous
//
#include <hip/hip_runtime.h>
#include <hip/hip_bf16.h>

#define D 128
#define NB 16  // nodes staged per block in node_tables

// wrT[m*64 + r] = dot(W[m, :], rel[r, :])   (m in [0,256), transposed layout)
__global__ __launch_bounds__(256) void compute_wr(const float* __restrict__ W,
                                                  const float* __restrict__ rel,
                                                  float* __restrict__ wrT) {
    int r = blockIdx.x;
    int m = threadIdx.x;
    const float4* wrow = (const float4*)(W + (size_t)m * D);
    const float4* rrow = (const float4*)(rel + (size_t)r * D);
    float s = 0.f;
#pragma unroll
    for (int k = 0; k < D / 4; ++k) {
        float4 a = wrow[k];
        float4 b = rrow[k];
        s += a.x * b.x + a.y * b.y + a.z * b.z + a.w * b.w;
    }
    wrT[(size_t)m * 64 + r] = s;
}

// Degree count
__global__ __launch_bounds__(256) void count_deg(const int* __restrict__ head,
                                                 const int* __restrict__ tail,
                                                 int* __restrict__ deg_u,
                                                 int* __restrict__ deg_i, int E) {
    int e = blockIdx.x * 256 + threadIdx.x;
    if (e >= E) return;
    atomicAdd(deg_u + head[e], 1);
    atomicAdd(deg_i + tail[e], 1);
}

// ---- two-level exclusive scan (N <= nb*4096, nb <= 64) ----
__global__ __launch_bounds__(1024) void scan_bsum(const int* __restrict__ deg,
                                                  int* __restrict__ bsum, int N) {
    __shared__ int lds[1024];
    int b = blockIdx.x, tid = threadIdx.x;
    int base = b * 4096 + tid * 4;
    int s = 0;
#pragma unroll
    for (int j = 0; j < 4; ++j) { int i = base + j; if (i < N) s += deg[i]; }
    lds[tid] = s;
    __syncthreads();
    for (int off = 1; off < 1024; off <<= 1) {
        int t = (tid >= off) ? lds[tid - off] : 0;
        __syncthreads();
        lds[tid] += t;
        __syncthreads();
    }
    if (tid == 1023) bsum[b] = lds[1023];
}

__global__ __launch_bounds__(64) void scan_off(const int* __restrict__ bsum,
                                               int* __restrict__ boff, int nb) {
    int tid = threadIdx.x;
    int v = (tid < nb) ? bsum[tid] : 0;
    int incl = v;
    for (int off = 1; off < 64; off <<= 1) {
        int t = __shfl_up(incl, off, 64);
        if (tid >= off) incl += t;
    }
    if (tid < nb) boff[tid] = incl - v;
    if (tid == 63) boff[nb] = incl;  // grand total
}

__global__ __launch_bounds__(1024) void scan_write(const int* __restrict__ deg,
                                                   const int* __restrict__ boff,
                                                   int* __restrict__ rowptr,
                                                   int* __restrict__ cur, int N, int nb) {
    __shared__ int lds[1024];
    int b = blockIdx.x, tid = threadIdx.x;
    int base = b * 4096 + tid * 4;
    int v[4];
    int s = 0;
#pragma unroll
    for (int j = 0; j < 4; ++j) { int i = base + j; v[j] = (i < N) ? deg[i] : 0; s += v[j]; }
    lds[tid] = s;
    __syncthreads();
    for (int off = 1; off < 1024; off <<= 1) {
        int t = (tid >= off) ? lds[tid - off] : 0;
        __syncthreads();
        lds[tid] += t;
        __syncthreads();
    }
    int run = boff[b] + lds[tid] - s;
#pragma unroll
    for (int j = 0; j < 4; ++j) {
        int i = base + j;
        if (i < N) { rowptr[i] = run; cur[i] = run; run += v[j]; }
    }
    if (b == 0 && tid == 0) rowptr[N] = boff[nb];
}

// Build permuted adjacency: adj[slot] = other-endpoint, pos[e] = slot of edge e.
__global__ __launch_bounds__(256) void fill_adj(const int* __restrict__ head,
                                                const int* __restrict__ tail,
                                                int* __restrict__ cur_u,
                                                int* __restrict__ cur_i,
                                                int* __restrict__ adj_u,
                                                int* __restrict__ adj_i,
                                                int* __restrict__ pos_u,
                                                int* __restrict__ pos_i, int E) {
    int e = blockIdx.x * 256 + threadIdx.x;
    if (e >= E) return;
    int h = head[e], t = tail[e];
    int su = atomicAdd(cur_u + h, 1);
    adj_u[su] = t;
    pos_u[e] = su;
    int si = atomicAdd(cur_i + t, 1);
    adj_i[si] = h;
    pos_i[e] = si;
}

// out[n*64 + r] = dot(rows[n,:], wrT[:,r]).  lane = r; wrT column held in 128
// VGPRs; node rows staged in LDS (16 nodes / 8 KB per group, register-prefetched);
// broadcast ds_read_b128 feeds 4 independent FMA chains.
__global__ __launch_bounds__(256, 3) void node_tables(const float* __restrict__ rows,
                                                      const float* __restrict__ wrT,
                                                      float* __restrict__ out, int N) {
    int lane = threadIdx.x & 63;
    int wave = threadIdx.x >> 6;
    float w[128];
#pragma unroll
    for (int kk = 0; kk < 128; ++kk) w[kk] = wrT[(size_t)kk * 64 + lane];

    __shared__ float lds[NB * D];  // 8 KB

    int ngroups = (N + NB - 1) / NB;
    int g = blockIdx.x;
    if (g >= ngroups) return;

    int i0 = threadIdx.x;        // float4 slot 0..255
    int i1 = threadIdx.x + 256;  // float4 slot 256..511

    float4 v0, v1;
    {
        const float4* gsrc = (const float4*)(rows + (size_t)g * NB * D);
        int maxslot = min(N - g * NB, NB) * (D / 4);
        v0 = (i0 < maxslot) ? gsrc[i0] : make_float4(0.f, 0.f, 0.f, 0.f);
        v1 = (i1 < maxslot) ? gsrc[i1] : make_float4(0.f, 0.f, 0.f, 0.f);
    }
    while (true) {
        ((float4*)lds)[i0] = v0;
        ((float4*)lds)[i1] = v1;
        __syncthreads();
        int gn = g + gridDim.x;
        if (gn < ngroups) {  // prefetch next group into registers (overlaps compute)
            const float4* gsrc = (const float4*)(rows + (size_t)gn * NB * D);
            int maxslot = min(N - gn * NB, NB) * (D / 4);
            v0 = (i0 < maxslot) ? gsrc[i0] : make_float4(0.f, 0.f, 0.f, 0.f);
            v1 = (i1 < maxslot) ? gsrc[i1] : make_float4(0.f, 0.f, 0.f, 0.f);
        }
        int n0 = g * NB;
#pragma unroll
        for (int i = 0; i < 4; ++i) {
            int nl = wave * 4 + i;
            const float4* rp = (const float4*)(lds + nl * D);
            float a0 = 0.f, a1 = 0.f, a2 = 0.f, a3 = 0.f;
#pragma unroll
            for (int j = 0; j < 32; ++j) {
                float4 v = rp[j];  // uniform addr -> broadcast ds_read_b128
                a0 += v.x * w[4 * j + 0];
                a1 += v.y * w[4 * j + 1];
                a2 += v.z * w[4 * j + 2];
                a3 += v.w * w[4 * j + 3];
            }
            int n = n0 + nl;
            if (n < N) out[(size_t)n * 64 + lane] = (a0 + a1) + (a2 + a3);
        }
        if (gn >= ngroups) break;
        __syncthreads();
        g = gn;
    }
}

// ew[pos[e]] = exp(leakyrelu(alpha[head,r] + beta[tail,r]))  (written in CSR order)
__global__ __launch_bounds__(256) void edge_weights(const int* __restrict__ head,
                                                    const int* __restrict__ tail,
                                                    const int* __restrict__ etype,
                                                    const int* __restrict__ pos_u,
                                                    const int* __restrict__ pos_i,
                                                    const float* __restrict__ alpha,
                                                    const float* __restrict__ beta,
                                                    float* __restrict__ ew_u,
                                                    float* __restrict__ ew_i, int E) {
    int e = blockIdx.x * 256 + threadIdx.x;
    if (e >= E) return;
    int h = head[e], t = tail[e], r = etype[e];
    float s = alpha[(size_t)h * 64 + r] + beta[(size_t)t * 64 + r];
    s = s > 0.f ? s : 0.2f * s;  // LeakyReLU(0.2)
    float ex = expf(s);
    ew_u[pos_u[e]] = ex;
    ew_i[pos_i[e]] = ex;
}

// One wavefront per destination node; streaming ew/adj + single-level row gather,
// 2-deep manual pipeline.
__global__ __launch_bounds__(256) void agg_nodes(const float* __restrict__ src_rows,
                                                 const float* __restrict__ self_rows,
                                                 const float* __restrict__ ew,
                                                 const int* __restrict__ rowptr,
                                                 const int* __restrict__ adj_src,
                                                 float* __restrict__ dst, int N) {
    int node = (int)((blockIdx.x * (size_t)blockDim.x + threadIdx.x) >> 6);
    int lane = threadIdx.x & 63;
    if (node >= N) return;
    int beg = rowptr[node];
    int end = rowptr[node + 1];
    float ax = 0.f, ay = 0.f, esum = 0.f;
    int p = beg;
    float w_cur = 0.f;
    float2 v_cur = make_float2(0.f, 0.f);
    if (p < end) {
        w_cur = ew[p];
        v_cur = ((const float2*)(src_rows + (size_t)adj_src[p] * D))[lane];
    }
    while (p < end) {
        int pn = p + 1;
        float w_n = 0.f;
        float2 v_n = make_float2(0.f, 0.f);
        if (pn < end) {  // next edge's loads issued before current FMAs retire
            w_n = ew[pn];
            v_n = ((const float2*)(src_rows + (size_t)adj_src[pn] * D))[lane];
        }
        ax += w_cur * v_cur.x;
        ay += w_cur * v_cur.y;
        esum += w_cur;
        w_cur = w_n;
        v_cur = v_n;
        p = pn;
    }
    float inv_e = (end > beg) ? 1.f / esum : 0.f;
    float2 self = ((const float2*)(self_rows + (size_t)node * D))[lane];
    float gx = ax * inv_e + self.x;
    float gy = ay * inv_e + self.y;
    float n2 = gx * gx + gy * gy;
#pragma unroll
    for (int off = 32; off; off >>= 1) n2 += __shfl_xor(n2, off, 64);
    float inv = 1.f / fmaxf(sqrtf(n2), 1e-8f);
    float2 o;
    o.x = self.x + gx * inv;
    o.y = self.y + gy * inv;
    ((float2*)(dst + (size_t)node * D))[lane] = o;
}

extern "C" void kernel_launch(void* const* d_in, const int* in_sizes, int n_in,
                              void* d_out, int out_size, void* d_ws, size_t ws_size,
                              hipStream_t stream) {
    const float* user = (const float*)d_in[0];
    const float* rel  = (const float*)d_in[1];
    const float* ent  = (const float*)d_in[2];
    const float* W    = (const float*)d_in[3];
    const int* eidx   = (const int*)d_in[4];
    const int* etype  = (const int*)d_in[5];

    int Nu = in_sizes[0] / D;
    int R  = in_sizes[1] / D;
    int Ne = in_sizes[2] / D;
    int E  = in_sizes[5];
    const int* head = eidx;
    const int* tail = eidx + E;

    float* out_usr = (float*)d_out;
    float* out_ent = out_usr + (size_t)Nu * D;

    // alpha/beta tables live in d_out (dead scratch until hop-1 aggs overwrite;
    // edge_weights reads them earlier in stream order).
    float* alpha = (float*)d_out;
    float* beta  = alpha + (size_t)Nu * 64;

    // Workspace layout (~119 MB)
    float* fp = (float*)d_ws;
    float* usr_ws = fp; fp += (size_t)Nu * D;
    float* ent_ws = fp; fp += (size_t)Ne * D;
    float* ew_u   = fp; fp += E;
    float* ew_i   = fp; fp += E;
    float* wrT    = fp; fp += (size_t)2 * D * 64;  // [256][64]
    int* ip = (int*)fp;
    int* deg_u    = ip; ip += Nu;  // contiguous with deg_i for one memset
    int* deg_i    = ip; ip += Ne;
    int* cur_u    = ip; ip += Nu;
    int* cur_i    = ip; ip += Ne;
    int* rowptr_u = ip; ip += Nu + 1;
    int* rowptr_i = ip; ip += Ne + 1;
    int* adj_u    = ip; ip += E;
    int* adj_i    = ip; ip += E;
    int* pos_u    = ip; ip += E;
    int* pos_i    = ip; ip += E;
    int* bsum_u   = ip; ip += 64;
    int* bsum_i   = ip; ip += 64;
    int* boff_u   = ip; ip += 65;
    int* boff_i   = ip; ip += 65;

    int nb_u = (Nu + 4095) / 4096;
    int nb_i = (Ne + 4095) / 4096;

    // ---- Build CSR + permuted adjacency (once; graph static across hops) ----
    hipMemsetAsync(deg_u, 0, (size_t)(Nu + Ne) * sizeof(int), stream);
    compute_wr<<<R, 256, 0, stream>>>(W, rel, wrT);
    count_deg<<<(E + 255) / 256, 256, 0, stream>>>(head, tail, deg_u, deg_i, E);
    scan_bsum<<<nb_u, 1024, 0, stream>>>(deg_u, bsum_u, Nu);
    scan_off<<<1, 64, 0, stream>>>(bsum_u, boff_u, nb_u);
    scan_write<<<nb_u, 1024, 0, stream>>>(deg_u, boff_u, rowptr_u, cur_u, Nu, nb_u);
    scan_bsum<<<nb_i, 1024, 0, stream>>>(deg_i, bsum_i, Ne);
    scan_off<<<1, 64, 0, stream>>>(bsum_i, boff_i, nb_i);
    scan_write<<<nb_i, 1024, 0, stream>>>(deg_i, boff_i, rowptr_i, cur_i, Ne, nb_i);
    fill_adj<<<(E + 255) / 256, 256, 0, stream>>>(head, tail, cur_u, cur_i,
                                                  adj_u, adj_i, pos_u, pos_i, E);

    int eb = (E + 255) / 256;

    // ---- Hop 0: inputs -> ws ----
    node_tables<<<768, 256, 0, stream>>>(user, wrT, alpha, Nu);
    node_tables<<<768, 256, 0, stream>>>(ent, wrT + (size_t)D * 64, beta, Ne);
    edge_weights<<<eb, 256, 0, stream>>>(head, tail, etype, pos_u, pos_i,
                                         alpha, beta, ew_u, ew_i, E);
    agg_nodes<<<(Nu + 3) / 4, 256, 0, stream>>>(ent, user, ew_u, rowptr_u, adj_u,
                                                usr_ws, Nu);
    agg_nodes<<<(Ne + 3) / 4, 256, 0, stream>>>(user, ent, ew_i, rowptr_i, adj_i,
                                                ent_ws, Ne);

    // ---- Hop 1: ws -> d_out ----
    node_tables<<<768, 256, 0, stream>>>(usr_ws, wrT, alpha, Nu);
    node_tables<<<768, 256, 0, stream>>>(ent_ws, wrT + (size_t)D * 64, beta, Ne);
    edge_weights<<<eb, 256, 0, stream>>>(head, tail, etype, pos_u, pos_i,
                                         alpha, beta, ew_u, ew_i, E);
    agg_nodes<<<(Nu + 3) / 4, 256, 0, stream>>>(ent_ws, usr_ws, ew_u, rowptr_u, adj_u,
                                                out_usr, Nu);
    agg_nodes<<<(Ne + 3) / 4, 256, 0, stream>>>(usr_ws, ent_ws, ew_i, rowptr_i, adj_i,
                                                out_ent, Ne);
}

// Round 6
// 861.336 us; speedup vs baseline: 1.5903x; 1.1430x over previous
//
#include <hip/hip_runtime.h>
#include <hip/hip_bf16.h>

#define D 128
#define NB 16  // nodes staged per block in node_tables

// wrT[m*64 + r] = dot(W[m, :], rel[r, :])   (m in [0,256), transposed layout)
__global__ __launch_bounds__(256) void compute_wr(const float* __restrict__ W,
                                                  const float* __restrict__ rel,
                                                  float* __restrict__ wrT) {
    int r = blockIdx.x;
    int m = threadIdx.x;
    const float4* wrow = (const float4*)(W + (size_t)m * D);
    const float4* rrow = (const float4*)(rel + (size_t)r * D);
    float s = 0.f;
#pragma unroll
    for (int k = 0; k < D / 4; ++k) {
        float4 a = wrow[k];
        float4 b = rrow[k];
        s += a.x * b.x + a.y * b.y + a.z * b.z + a.w * b.w;
    }
    wrT[(size_t)m * 64 + r] = s;
}

// Degree count into combined array: deg[head[e]]++, deg[Nu + tail[e]]++
__global__ __launch_bounds__(256) void count_deg(const int* __restrict__ head,
                                                 const int* __restrict__ tail,
                                                 int* __restrict__ deg, int Nu, int E) {
    int e = blockIdx.x * 256 + threadIdx.x;
    if (e >= E) return;
    atomicAdd(deg + head[e], 1);
    atomicAdd(deg + Nu + tail[e], 1);
}

// ---- two-level exclusive scan (N <= nb*4096, nb <= 64) ----
__global__ __launch_bounds__(1024) void scan_bsum(const int* __restrict__ deg,
                                                  int* __restrict__ bsum, int N) {
    __shared__ int lds[1024];
    int b = blockIdx.x, tid = threadIdx.x;
    int base = b * 4096 + tid * 4;
    int s = 0;
#pragma unroll
    for (int j = 0; j < 4; ++j) { int i = base + j; if (i < N) s += deg[i]; }
    lds[tid] = s;
    __syncthreads();
    for (int off = 1; off < 1024; off <<= 1) {
        int t = (tid >= off) ? lds[tid - off] : 0;
        __syncthreads();
        lds[tid] += t;
        __syncthreads();
    }
    if (tid == 1023) bsum[b] = lds[1023];
}

__global__ __launch_bounds__(64) void scan_off(const int* __restrict__ bsum,
                                               int* __restrict__ boff, int nb) {
    int tid = threadIdx.x;
    int v = (tid < nb) ? bsum[tid] : 0;
    int incl = v;
    for (int off = 1; off < 64; off <<= 1) {
        int t = __shfl_up(incl, off, 64);
        if (tid >= off) incl += t;
    }
    if (tid < nb) boff[tid] = incl - v;
    if (tid == 63) boff[nb] = incl;  // grand total
}

__global__ __launch_bounds__(1024) void scan_write(const int* __restrict__ deg,
                                                   const int* __restrict__ boff,
                                                   int* __restrict__ rowptr,
                                                   int* __restrict__ cur, int N, int nb) {
    __shared__ int lds[1024];
    int b = blockIdx.x, tid = threadIdx.x;
    int base = b * 4096 + tid * 4;
    int v[4];
    int s = 0;
#pragma unroll
    for (int j = 0; j < 4; ++j) { int i = base + j; v[j] = (i < N) ? deg[i] : 0; s += v[j]; }
    lds[tid] = s;
    __syncthreads();
    for (int off = 1; off < 1024; off <<= 1) {
        int t = (tid >= off) ? lds[tid - off] : 0;
        __syncthreads();
        lds[tid] += t;
        __syncthreads();
    }
    int run = boff[b] + lds[tid] - s;
#pragma unroll
    for (int j = 0; j < 4; ++j) {
        int i = base + j;
        if (i < N) { rowptr[i] = run; cur[i] = run; run += v[j]; }
    }
    if (b == 0 && tid == 0) rowptr[N] = boff[nb];
}

// Combined adjacency: slot -> (other_endpoint, edge_id). u-slots in [0,E), i in [E,2E).
__global__ __launch_bounds__(256) void fill_adj(const int* __restrict__ head,
                                                const int* __restrict__ tail,
                                                int* __restrict__ cur,
                                                int2* __restrict__ adj, int Nu, int E) {
    int e = blockIdx.x * 256 + threadIdx.x;
    if (e >= E) return;
    int h = head[e], t = tail[e];
    int su = atomicAdd(cur + h, 1);
    adj[su] = make_int2(t, e);
    int si = atomicAdd(cur + Nu + t, 1);
    adj[si] = make_int2(h, e);
}

// out[n*64 + r] = dot(rows[n,:], wrT[:,r]).  lane = r; wrT column in 128 VGPRs;
// node rows staged in LDS; broadcast ds_read_b128 feeds 4 FMA chains.
__global__ __launch_bounds__(256, 3) void node_tables(const float* __restrict__ rows,
                                                      const float* __restrict__ wrT,
                                                      float* __restrict__ out, int N) {
    int lane = threadIdx.x & 63;
    int wave = threadIdx.x >> 6;
    float w[128];
#pragma unroll
    for (int kk = 0; kk < 128; ++kk) w[kk] = wrT[(size_t)kk * 64 + lane];

    __shared__ float lds[NB * D];  // 8 KB

    int ngroups = (N + NB - 1) / NB;
    int g = blockIdx.x;
    if (g >= ngroups) return;

    int i0 = threadIdx.x;
    int i1 = threadIdx.x + 256;

    float4 v0, v1;
    {
        const float4* gsrc = (const float4*)(rows + (size_t)g * NB * D);
        int maxslot = min(N - g * NB, NB) * (D / 4);
        v0 = (i0 < maxslot) ? gsrc[i0] : make_float4(0.f, 0.f, 0.f, 0.f);
        v1 = (i1 < maxslot) ? gsrc[i1] : make_float4(0.f, 0.f, 0.f, 0.f);
    }
    while (true) {
        ((float4*)lds)[i0] = v0;
        ((float4*)lds)[i1] = v1;
        __syncthreads();
        int gn = g + gridDim.x;
        if (gn < ngroups) {
            const float4* gsrc = (const float4*)(rows + (size_t)gn * NB * D);
            int maxslot = min(N - gn * NB, NB) * (D / 4);
            v0 = (i0 < maxslot) ? gsrc[i0] : make_float4(0.f, 0.f, 0.f, 0.f);
            v1 = (i1 < maxslot) ? gsrc[i1] : make_float4(0.f, 0.f, 0.f, 0.f);
        }
        int n0 = g * NB;
#pragma unroll
        for (int i = 0; i < 4; ++i) {
            int nl = wave * 4 + i;
            const float4* rp = (const float4*)(lds + nl * D);
            float a0 = 0.f, a1 = 0.f, a2 = 0.f, a3 = 0.f;
#pragma unroll
            for (int j = 0; j < 32; ++j) {
                float4 v = rp[j];
                a0 += v.x * w[4 * j + 0];
                a1 += v.y * w[4 * j + 1];
                a2 += v.z * w[4 * j + 2];
                a3 += v.w * w[4 * j + 3];
            }
            int n = n0 + nl;
            if (n < N) out[(size_t)n * 64 + lane] = (a0 + a1) + (a2 + a3);
        }
        if (gn >= ngroups) break;
        __syncthreads();
        g = gn;
    }
}

// ew[e] = exp(leakyrelu(alpha[head,r] + beta[tail,r]))  -- coalesced edge-order write
__global__ __launch_bounds__(256) void edge_weights(const int* __restrict__ head,
                                                    const int* __restrict__ tail,
                                                    const int* __restrict__ etype,
                                                    const float* __restrict__ alpha,
                                                    const float* __restrict__ beta,
                                                    float* __restrict__ ew, int E) {
    int e = blockIdx.x * 256 + threadIdx.x;
    if (e >= E) return;
    int h = head[e], t = tail[e], r = etype[e];
    float s = alpha[(size_t)h * 64 + r] + beta[(size_t)t * 64 + r];
    s = s > 0.f ? s : 0.2f * s;  // LeakyReLU(0.2)
    ew[e] = expf(s);
}

// Fused both-sides aggregation. One wave per node (wid<Nu: user, else entity).
// Half-wave scheme: lanes 0-31 process edge p, lanes 32-63 edge p+1 (float4/lane).
__global__ __launch_bounds__(256) void agg_nodes(const float* __restrict__ usr_rows,
                                                 const float* __restrict__ ent_rows,
                                                 const float* __restrict__ ew,
                                                 const int* __restrict__ rowptr,
                                                 const int2* __restrict__ adj,
                                                 float* __restrict__ dst_u,
                                                 float* __restrict__ dst_e,
                                                 int Nu, int Ntot) {
    int wid = (int)((blockIdx.x * (size_t)blockDim.x + threadIdx.x) >> 6);
    int lane = threadIdx.x & 63;
    if (wid >= Ntot) return;
    int half = lane >> 5, li = lane & 31;
    const float* src;
    const float* self;
    float* dst;
    int node;
    if (wid < Nu) { node = wid;      src = ent_rows; self = usr_rows; dst = dst_u; }
    else          { node = wid - Nu; src = usr_rows; self = ent_rows; dst = dst_e; }
    int beg = rowptr[wid], end = rowptr[wid + 1];

    float4 acc = make_float4(0.f, 0.f, 0.f, 0.f);
    float esum = 0.f;
    int p = beg;
    float w_c = 0.f;
    float4 v_c = make_float4(0.f, 0.f, 0.f, 0.f);
    if (p < end) {
        int srcn = 0;
        int pe = p + half;
        if (pe < end) { int2 a = adj[pe]; srcn = a.x; w_c = ew[a.y]; }
        v_c = ((const float4*)(src + (size_t)srcn * D))[li];
    }
    while (p < end) {
        int pn = p + 2;
        float w_n = 0.f;
        float4 v_n = make_float4(0.f, 0.f, 0.f, 0.f);
        if (pn < end) {  // next pair's loads issued before current FMAs retire
            int srcn = 0;
            int pe = pn + half;
            if (pe < end) { int2 a = adj[pe]; srcn = a.x; w_n = ew[a.y]; }
            v_n = ((const float4*)(src + (size_t)srcn * D))[li];
        }
        acc.x += w_c * v_c.x;
        acc.y += w_c * v_c.y;
        acc.z += w_c * v_c.z;
        acc.w += w_c * v_c.w;
        esum += w_c;
        w_c = w_n;
        v_c = v_n;
        p = pn;
    }
    // combine the two half-wave partials (both halves end up with totals)
    esum += __shfl_xor(esum, 32, 64);
    acc.x += __shfl_xor(acc.x, 32, 64);
    acc.y += __shfl_xor(acc.y, 32, 64);
    acc.z += __shfl_xor(acc.z, 32, 64);
    acc.w += __shfl_xor(acc.w, 32, 64);
    float inv_e = (end > beg) ? 1.f / esum : 0.f;
    float4 s4 = ((const float4*)(self + (size_t)node * D))[li];
    float4 g;
    g.x = acc.x * inv_e + s4.x;
    g.y = acc.y * inv_e + s4.y;
    g.z = acc.z * inv_e + s4.z;
    g.w = acc.w * inv_e + s4.w;
    float n2 = g.x * g.x + g.y * g.y + g.z * g.z + g.w * g.w;
#pragma unroll
    for (int off = 16; off; off >>= 1) n2 += __shfl_xor(n2, off, 64);
    float inv = 1.f / fmaxf(sqrtf(n2), 1e-8f);
    if (half == 0) {
        float4 o;
        o.x = s4.x + g.x * inv;
        o.y = s4.y + g.y * inv;
        o.z = s4.z + g.z * inv;
        o.w = s4.w + g.w * inv;
        ((float4*)(dst + (size_t)node * D))[li] = o;
    }
}

extern "C" void kernel_launch(void* const* d_in, const int* in_sizes, int n_in,
                              void* d_out, int out_size, void* d_ws, size_t ws_size,
                              hipStream_t stream) {
    const float* user = (const float*)d_in[0];
    const float* rel  = (const float*)d_in[1];
    const float* ent  = (const float*)d_in[2];
    const float* W    = (const float*)d_in[3];
    const int* eidx   = (const int*)d_in[4];
    const int* etype  = (const int*)d_in[5];

    int Nu = in_sizes[0] / D;
    int R  = in_sizes[1] / D;
    int Ne = in_sizes[2] / D;
    int E  = in_sizes[5];
    int Ntot = Nu + Ne;
    const int* head = eidx;
    const int* tail = eidx + E;

    float* out_usr = (float*)d_out;
    float* out_ent = out_usr + (size_t)Nu * D;

    // alpha/beta tables live in d_out (dead scratch until hop-1 aggs overwrite;
    // edge_weights reads them earlier in stream order).
    float* alpha = (float*)d_out;
    float* beta  = alpha + (size_t)Nu * 64;

    // Workspace layout (~117 MB)
    float* fp = (float*)d_ws;
    float* usr_ws = fp; fp += (size_t)Nu * D;
    float* ent_ws = fp; fp += (size_t)Ne * D;
    float* ew     = fp; fp += E;
    float* wrT    = fp; fp += (size_t)2 * D * 64;  // [256][64]
    int* ip = (int*)fp;
    int* deg    = ip; ip += Ntot;
    int* cur    = ip; ip += Ntot;
    int* rowptr = ip; ip += Ntot + 1;
    int2* adj   = (int2*)ip; ip += 4 * E;  // 2E int2 slots
    int* bsum   = ip; ip += 64;
    int* boff   = ip; ip += 65;

    int nb = (Ntot + 4095) / 4096;  // <= 64

    // ---- Build combined CSR + adjacency (once; graph static across hops) ----
    hipMemsetAsync(deg, 0, (size_t)Ntot * sizeof(int), stream);
    compute_wr<<<R, 256, 0, stream>>>(W, rel, wrT);
    count_deg<<<(E + 255) / 256, 256, 0, stream>>>(head, tail, deg, Nu, E);
    scan_bsum<<<nb, 1024, 0, stream>>>(deg, bsum, Ntot);
    scan_off<<<1, 64, 0, stream>>>(bsum, boff, nb);
    scan_write<<<nb, 1024, 0, stream>>>(deg, boff, rowptr, cur, Ntot, nb);
    fill_adj<<<(E + 255) / 256, 256, 0, stream>>>(head, tail, cur, adj, Nu, E);

    int eb = (E + 255) / 256;
    int ab = (Ntot + 3) / 4;  // 4 waves (nodes) per block

    // ---- Hop 0: inputs -> ws ----
    node_tables<<<768, 256, 0, stream>>>(user, wrT, alpha, Nu);
    node_tables<<<768, 256, 0, stream>>>(ent, wrT + (size_t)D * 64, beta, Ne);
    edge_weights<<<eb, 256, 0, stream>>>(head, tail, etype, alpha, beta, ew, E);
    agg_nodes<<<ab, 256, 0, stream>>>(user, ent, ew, rowptr, adj,
                                      usr_ws, ent_ws, Nu, Ntot);

    // ---- Hop 1: ws -> d_out ----
    node_tables<<<768, 256, 0, stream>>>(usr_ws, wrT, alpha, Nu);
    node_tables<<<768, 256, 0, stream>>>(ent_ws, wrT + (size_t)D * 64, beta, Ne);
    edge_weights<<<eb, 256, 0, stream>>>(head, tail, etype, alpha, beta, ew, E);
    agg_nodes<<<ab, 256, 0, stream>>>(usr_ws, ent_ws, ew, rowptr, adj,
                                      out_usr, out_ent, Nu, Ntot);
}